// Round 7
// baseline (11812.782 us; speedup 1.0000x reference)
//
#include <hip/hip_runtime.h>

constexpr int kB   = 32;    // batch
constexpr int kNS  = 100;   // n_support
constexpr int kNW  = 10;    // n_way
constexpr int kNZ  = 1000;  // kNS*kNW
constexpr int kD   = 512;   // feature dim
constexpr int kNQ  = 150;   // N*Q query rows
constexpr int kIt  = 15;    // IPM iterations
constexpr int kHalf = 50;
constexpr int kP   = 102;   // LDS column pitch (doubles): 816B stride ->
                            // 8 consecutive lanes hit 8 disjoint 4-bank
                            // windows for b128 -> conflict-free

// -------------------------------------------------------------------------
// K[b][i][j] = <sup_i, sup_j>  (fp32 accumulate, stored fp64 for the IPM)
__global__ __launch_bounds__(128) void gram_kernel(const float* __restrict__ sup,
                                                   double* __restrict__ K64)
{
    const int i = blockIdx.x;
    const int b = blockIdx.y;
    const int tid = threadIdx.x;
    __shared__ float rowi[kD];
    const float* supb = sup + (size_t)b * kNS * kD;
    reinterpret_cast<float4*>(rowi)[tid] =
        reinterpret_cast<const float4*>(supb + (size_t)i * kD)[tid];
    __syncthreads();
    for (int j = tid; j < kNS; j += 128) {
        const float4* rj = reinterpret_cast<const float4*>(supb + (size_t)j * kD);
        float acc = 0.0f;
        for (int d4 = 0; d4 < kD / 4; ++d4) {
            float4 v = rj[d4];
            acc += rowi[4*d4+0]*v.x + rowi[4*d4+1]*v.y
                 + rowi[4*d4+2]*v.z + rowi[4*d4+3]*v.w;
        }
        K64[((size_t)b * kNS + i) * kNS + j] = (double)acc;
    }
}

// compat[b][i][q] = <sup_i, qry_q>
__global__ __launch_bounds__(256) void compat_kernel(const float* __restrict__ sup,
                                                     const float* __restrict__ qry,
                                                     float* __restrict__ compat)
{
    const int i = blockIdx.x;
    const int b = blockIdx.y;
    const int tid = threadIdx.x;
    __shared__ float rowi[kD];
    const float* supb = sup + (size_t)b * kNS * kD;
    const float* qryb = qry + (size_t)b * kNQ * kD;
    if (tid < 128)
        reinterpret_cast<float4*>(rowi)[tid] =
            reinterpret_cast<const float4*>(supb + (size_t)i * kD)[tid];
    __syncthreads();
    for (int j = tid; j < kNQ; j += 256) {
        const float4* rj = reinterpret_cast<const float4*>(qryb + (size_t)j * kD);
        float acc = 0.0f;
        for (int d4 = 0; d4 < kD / 4; ++d4) {
            float4 v = rj[d4];
            acc += rowi[4*d4+0]*v.x + rowi[4*d4+1]*v.y
                 + rowi[4*d4+2]*v.z + rowi[4*d4+3]*v.w;
        }
        compat[((size_t)b * kNS + i) * kNQ + j] = acc;
    }
}

__global__ __launch_bounds__(256) void init_kernel(double* __restrict__ z,
                                                   double* __restrict__ nu,
                                                   double* __restrict__ s,
                                                   double* __restrict__ lam,
                                                   double* __restrict__ mu_g)
{
    const int b = blockIdx.x;
    const int tid = threadIdx.x;
    for (int m = tid; m < kNZ; m += 256) {
        z[b*kNZ + m]   = 0.0;
        s[b*kNZ + m]   = 1.0;
        lam[b*kNZ + m] = 1.0;
    }
    if (tid < kNS) nu[b*kNS + tid] = 0.0;
    if (tid == 0)  mu_g[b] = 1.0;   // dot(s0,lam0)/kNZ
}

// -------------------------------------------------------------------------
// Wave-synchronous in-place Gauss-Jordan inverse (no pivoting; SPD-safe).
// One wave; lane j owns columns j and j+64 (second masked past NCOL).
// Per pivot k (standard gaussj recurrence, column view):
//   pinv = 1/M[k][k];  c_i = old col k (broadcast read)
//   col j!=k: M[i][j] = M[i][j] - c_i*(M[k][j]*pinv);  M[k][j] = M[k][j]*pinv
//   col k   : M[i][k] = -c_i*pinv;                     M[k][k] = pinv
// Unified: newv_i = own_i*s - c_i*mult  (s=0,mult=pinv for pivot col;
// s=1,mult=nr otherwise), then patch element i==k to mult afterwards
// (LDS ops from one wave process in order; compiler orders aliasing ops).
template <int NCOL>
__device__ __forceinline__ void wave_gj(double* M, int j)
{
    const int j2 = j + 64;
    const bool act2 = (j2 < NCOL);
    const int js2 = act2 ? j2 : j;
    double* c1 = M + j   * kP;
    double* c2 = M + js2 * kP;

    #pragma unroll 1
    for (int k = 0; k < kNS; ++k) {
        const double* ck = M + k * kP;
        const double piv = ck[k];               // broadcast
        const double pinv = 1.0 / piv;
        const double m1 = c1[k];
        const double m2 = c2[k];
        const bool jk1 = (j == k), jk2 = (js2 == k);
        const double mult1 = jk1 ? pinv : m1 * pinv;
        const double mult2 = jk2 ? pinv : m2 * pinv;
        const double s1 = jk1 ? 0.0 : 1.0;
        const double s2 = jk2 ? 0.0 : 1.0;
        // 4 chunks of 32 rows (last = 4 rows); loads batched ahead of FMAs
        #pragma unroll
        for (int ch = 0; ch < 4; ++ch) {
            const int i0 = ch * 32;
            const int n2 = (ch == 3) ? 2 : 16;   // double2 count
            double2 cb[16], o1[16], o2[16];
            const double2* cbp = (const double2*)(ck + i0);
            const double2* p1  = (const double2*)(c1 + i0);
            const double2* p2  = (const double2*)(c2 + i0);
            #pragma unroll
            for (int q = 0; q < 16; ++q) {
                if (q < n2) { cb[q] = cbp[q]; o1[q] = p1[q]; o2[q] = p2[q]; }
            }
            #pragma unroll
            for (int q = 0; q < 16; ++q) {
                if (q < n2) {
                    double2 r1v, r2v;
                    r1v.x = o1[q].x * s1 - cb[q].x * mult1;
                    r1v.y = o1[q].y * s1 - cb[q].y * mult1;
                    r2v.x = o2[q].x * s2 - cb[q].x * mult2;
                    r2v.y = o2[q].y * s2 - cb[q].y * mult2;
                    ((double2*)(c1 + i0))[q] = r1v;
                    if (act2) ((double2*)(c2 + i0))[q] = r2v;
                }
            }
        }
        c1[k] = mult1;                 // fix row-k element (was computed generically)
        if (act2) c2[k] = mult2;
    }
}

// -------------------------------------------------------------------------
// One WAVE per (b,a): build H_a = K + diag(1+lam/s) in LDS (col-major),
// fused (K z_a) for r1, barrier-free GJ inverse, t_a = Hinv r1, write Hinv.
// Pads: M[c][100] = r1[c], M[c][101] = z_a[c].
__global__ __launch_bounds__(64) void ipm_invert_kernel(
    const double* __restrict__ K64, const int* __restrict__ labels,
    const double* __restrict__ z, const double* __restrict__ nu,
    const double* __restrict__ s, const double* __restrict__ lam,
    const double* __restrict__ mu_g,
    double* __restrict__ Hinv, double* __restrict__ tvec)
{
    const int b = blockIdx.x / kNW;
    const int a = blockIdx.x - b * kNW;
    const int j = threadIdx.x;
    const int j2 = j + 64;
    const bool act2 = (j2 < kNS);
    const int js2 = act2 ? j2 : j;

    __shared__ alignas(16) double M[kNS * kP];   // 81,600 B -> 2 blocks/CU

    const double* Kb = K64 + (size_t)b * kNS * kNS;
    // load K linear-coalesced, scatter to col-major: M[c][r] = K[r][c]
    for (int e = j; e < kNS * kNS; e += 64) {
        int r = e / kNS, c = e - r * kNS;
        M[c * kP + r] = Kb[e];
    }
    for (int e = j; e < kNS; e += 64)
        M[e * kP + 101] = z[(size_t)b * kNZ + e * kNW + a];

    // kz_j = (K z_a)_j via own-column dot with broadcast z (K symmetric)
    double kz1 = 0.0, kz2 = 0.0;
    #pragma unroll 4
    for (int i = 0; i < kNS; ++i) {
        const double zi = M[i * kP + 101];
        kz1 += M[j   * kP + i] * zi;
        kz2 += M[js2 * kP + i] * zi;
    }
    const double mu = mu_g[b];
    {   // col j: diag add + r1
        const size_t m = (size_t)b * kNZ + j * kNW + a;
        const double zv = M[j * kP + 101];
        const double sv = s[m], lv = lam[m];
        M[j * kP + j] += 1.0 + lv / sv;
        const double yv = (labels[b * kNS + j] == a) ? 1.0 : 0.0;
        const double rd = kz1 + zv - yv + lv + nu[b * kNS + j];
        const double rp = zv + sv - 0.1 * yv;
        const double rc = lv * sv - 0.1 * mu;
        M[j * kP + 100] = -rd + (rc - lv * rp) / sv;
    }
    if (act2) {   // col j2
        const size_t m = (size_t)b * kNZ + j2 * kNW + a;
        const double zv = M[j2 * kP + 101];
        const double sv = s[m], lv = lam[m];
        M[j2 * kP + j2] += 1.0 + lv / sv;
        const double yv = (labels[b * kNS + j2] == a) ? 1.0 : 0.0;
        const double rd = kz2 + zv - yv + lv + nu[b * kNS + j2];
        const double rp = zv + sv - 0.1 * yv;
        const double rc = lv * sv - 0.1 * mu;
        M[j2 * kP + 100] = -rd + (rc - lv * rp) / sv;
    }

    wave_gj<kNS>(M, j);

    // t_a = Hinv r1 (Hinv symmetric: t_j = dot(col j, r1))
    double t1 = 0.0, t2 = 0.0;
    #pragma unroll 4
    for (int i = 0; i < kNS; ++i) {
        const double r1i = M[i * kP + 100];
        t1 += M[j   * kP + i] * r1i;
        t2 += M[js2 * kP + i] * r1i;
    }
    double* tv = tvec + (size_t)(b * kNW + a) * kNS;
    tv[j] = t1;
    if (act2) tv[j2] = t2;

    // write Hinv row-major, coalesced across lanes
    double* Hg = Hinv + (size_t)(b * kNW + a) * kNS * kNS;
    #pragma unroll 2
    for (int i = 0; i < kNS; ++i) {
        Hg[i * kNS + j] = M[j * kP + i];
        if (act2) Hg[i * kNS + j2] = M[js2 * kP + i];
    }
}

// -------------------------------------------------------------------------
// One WAVE per b: S = sum_a Hinv_a built on load (absorbs sbuild), rhs as
// column 100 (non-pivot -> receives pure row ops -> solution), GJ, dnu out.
__global__ __launch_bounds__(64) void schur_solve_kernel(
    const double* __restrict__ Hinv, const double* __restrict__ tvec,
    const double* __restrict__ z, double* __restrict__ dnu_g)
{
    const int b = blockIdx.x;
    const int j = threadIdx.x;
    __shared__ alignas(16) double M[(kNS + 1) * kP];   // 82,416 B

    const double* Hb = Hinv + (size_t)b * kNW * kNS * kNS;
    for (int e = j; e < kNS * kNS; e += 64) {
        int r = e / kNS, c = e - r * kNS;
        double acc = 0.0;
        #pragma unroll
        for (int a = 0; a < kNW; ++a) acc += Hb[(size_t)a * kNS * kNS + e];
        M[c * kP + r] = acc;
    }
    const double* tb = tvec + (size_t)b * kNW * kNS;
    const double* zb = z + (size_t)b * kNZ;
    for (int e = j; e < kNS; e += 64) {
        double acc = 0.0;
        #pragma unroll
        for (int a = 0; a < kNW; ++a) acc += tb[a * kNS + e] + zb[e * kNW + a];
        M[kNS * kP + e] = acc;    // rhs = sum_a t_a + rp2
    }

    wave_gj<kNS + 1>(M, j);

    for (int e = j; e < kNS; e += 64)
        dnu_g[(size_t)b * kNS + e] = M[kNS * kP + e];
}

// -------------------------------------------------------------------------
// One block per (b,a): dz_a = t_a - Hinv_a*dnu (full-GPU streaming of Hinv),
// ds/dlam, per-block min step-ratio.
__global__ __launch_bounds__(256) void dz_kernel(
    const int* __restrict__ labels,
    const double* __restrict__ Hinv, const double* __restrict__ tvec,
    const double* __restrict__ dnu_g,
    const double* __restrict__ z, const double* __restrict__ s,
    const double* __restrict__ lam, const double* __restrict__ mu_g,
    double* __restrict__ dz_g, double* __restrict__ ds_g,
    double* __restrict__ dl_g, double* __restrict__ minr_g)
{
    const int b = blockIdx.x / kNW;
    const int a = blockIdx.x - b * kNW;
    const int tid = threadIdx.x;
    const int h = tid >> 7;
    const int j = tid & 127;

    __shared__ double dnus[kNS];
    __shared__ double p2[2][kNS];
    __shared__ double red[256];

    const double* Hb = Hinv + (size_t)(b * kNW + a) * kNS * kNS;

    if (tid < kNS) dnus[tid] = dnu_g[(size_t)b * kNS + tid];
    __syncthreads();

    if (j < kNS) {
        double p = 0.0;
        #pragma unroll
        for (int r = 0; r < kHalf; ++r)
            p += Hb[(size_t)(h * kHalf + r) * kNS + j] * dnus[h * kHalf + r];
        p2[h][j] = p;
    }
    __syncthreads();

    double lmin = 1e300;
    if (tid < kNS) {
        const int i = tid;
        const size_t m = (size_t)b * kNZ + i * kNW + a;
        const double mu = mu_g[b];
        double dz = tvec[(size_t)(b * kNW + a) * kNS + i] - (p2[0][i] + p2[1][i]);
        double yv = (labels[b * kNS + i] == a) ? 1.0 : 0.0;
        double zv = z[m], sv = s[m], lv = lam[m];
        double rp = zv + sv - 0.1 * yv;
        double rc = lv * sv - 0.1 * mu;
        double ds = -rp - dz;
        double dl = (-rc - lv * ds) / sv;
        dz_g[m] = dz; ds_g[m] = ds; dl_g[m] = dl;
        if (ds < 0.0) lmin = fmin(lmin, -sv / ds);
        if (dl < 0.0) lmin = fmin(lmin, -lv / dl);
    }
    red[tid] = lmin; __syncthreads();
    for (int off = 128; off > 0; off >>= 1) {
        if (tid < off) red[tid] = fmin(red[tid], red[tid + off]);
        __syncthreads();
    }
    if (tid == 0) minr_g[b * kNW + a] = red[0];
}

// -------------------------------------------------------------------------
// One block per b: alpha from the 10 per-class mins, state update, next mu.
__global__ __launch_bounds__(256) void update_kernel(
    const double* __restrict__ minr_g, const double* __restrict__ dnu_g,
    const double* __restrict__ dz_g, const double* __restrict__ ds_g,
    const double* __restrict__ dl_g,
    double* __restrict__ z, double* __restrict__ nu,
    double* __restrict__ s, double* __restrict__ lam,
    double* __restrict__ mu_g)
{
    const int b = blockIdx.x;
    const int tid = threadIdx.x;
    __shared__ double red[256];

    double am = 1e300;
    #pragma unroll
    for (int a = 0; a < kNW; ++a) am = fmin(am, minr_g[b * kNW + a]);
    const double alpha = fmin(1.0, 0.99 * am);

    double* zb = z   + (size_t)b * kNZ;
    double* sb = s   + (size_t)b * kNZ;
    double* lb = lam + (size_t)b * kNZ;

    double md = 0.0;
    #pragma unroll
    for (int tcl = 0; tcl < 4; ++tcl) {
        const int  e = tid + tcl * 256;
        const size_t m = (size_t)b * kNZ + e;
        if (e < kNZ) {
            double zn = zb[e] + alpha * dz_g[m];
            double sn = sb[e] + alpha * ds_g[m];
            double ln = lb[e] + alpha * dl_g[m];
            zb[e] = zn; sb[e] = sn; lb[e] = ln;
            md += sn * ln;
        }
    }
    red[tid] = md; __syncthreads();
    for (int off = 128; off > 0; off >>= 1) {
        if (tid < off) red[tid] += red[tid + off];
        __syncthreads();
    }
    if (tid == 0) mu_g[b] = red[0] / kNZ;
    if (tid < kNS) nu[(size_t)b * kNS + tid] += alpha * dnu_g[(size_t)b * kNS + tid];
}

// -------------------------------------------------------------------------
// logits[b][q][n] = sum_s compat[b][s][q] * z[b][s*10+n]
__global__ __launch_bounds__(256) void logits_kernel(const float* __restrict__ compat,
                                                     const double* __restrict__ z,
                                                     float* __restrict__ out)
{
    const int b = blockIdx.x;
    const int tid = threadIdx.x;
    const float* cb = compat + (size_t)b * kNS * kNQ;
    const double* zb = z + (size_t)b * kNZ;
    __shared__ double zs[kNZ];
    for (int m = tid; m < kNZ; m += 256) zs[m] = zb[m];
    __syncthreads();
    for (int idx = tid; idx < kNQ * kNW; idx += 256) {
        int q = idx / kNW, n = idx - q * kNW;
        double acc = 0.0;
        for (int s2 = 0; s2 < kNS; ++s2)
            acc += (double)cb[(size_t)s2 * kNQ + q] * zs[s2 * kNW + n];
        out[(size_t)b * kNQ * kNW + idx] = (float)acc;
    }
}

// -------------------------------------------------------------------------
extern "C" void kernel_launch(void* const* d_in, const int* in_sizes, int n_in,
                              void* d_out, int out_size, void* d_ws, size_t ws_size,
                              hipStream_t stream)
{
    const float* sup    = (const float*)d_in[0];   // (32,10,10,512)
    const int*   labels = (const int*)  d_in[1];   // (32,10,10)
    const float* qry    = (const float*)d_in[2];   // (32,10,15,512)
    float* out = (float*)d_out;                    // (32,150,10) fp32

    char* ws = (char*)d_ws;
    size_t off = 0;
    auto alloc = [&](size_t bytes) -> void* {
        void* p = ws + off;
        off += (bytes + 255) & ~(size_t)255;
        return p;
    };
    double* K64    = (double*)alloc(sizeof(double) * kB * kNS * kNS);        // 2.56 MB
    double* z      = (double*)alloc(sizeof(double) * kB * kNZ);
    double* nu     = (double*)alloc(sizeof(double) * kB * kNS);
    double* s      = (double*)alloc(sizeof(double) * kB * kNZ);
    double* lam    = (double*)alloc(sizeof(double) * kB * kNZ);
    double* mu_g   = (double*)alloc(sizeof(double) * kB);
    double* Hinv   = (double*)alloc(sizeof(double) * kB * kNW * kNS * kNS);  // 25.6 MB
    double* tvec   = (double*)alloc(sizeof(double) * kB * kNW * kNS);
    double* dnu_g  = (double*)alloc(sizeof(double) * kB * kNS);
    double* dz_g   = (double*)alloc(sizeof(double) * kB * kNZ);
    double* ds_g   = (double*)alloc(sizeof(double) * kB * kNZ);
    double* dl_g   = (double*)alloc(sizeof(double) * kB * kNZ);
    double* minr_g = (double*)alloc(sizeof(double) * kB * kNW);
    float*  compat = (float*) alloc(sizeof(float)  * kB * kNS * kNQ);        // 1.92 MB

    gram_kernel  <<<dim3(kNS, kB), 128, 0, stream>>>(sup, K64);
    compat_kernel<<<dim3(kNS, kB), 256, 0, stream>>>(sup, qry, compat);
    init_kernel  <<<kB, 256, 0, stream>>>(z, nu, s, lam, mu_g);

    for (int it = 0; it < kIt; ++it) {
        ipm_invert_kernel<<<kB * kNW, 64, 0, stream>>>(K64, labels, z, nu, s,
                                                       lam, mu_g, Hinv, tvec);
        schur_solve_kernel<<<kB, 64, 0, stream>>>(Hinv, tvec, z, dnu_g);
        dz_kernel<<<kB * kNW, 256, 0, stream>>>(labels, Hinv, tvec, dnu_g,
                                                z, s, lam, mu_g,
                                                dz_g, ds_g, dl_g, minr_g);
        update_kernel<<<kB, 256, 0, stream>>>(minr_g, dnu_g, dz_g, ds_g, dl_g,
                                              z, nu, s, lam, mu_g);
    }

    logits_kernel<<<kB, 256, 0, stream>>>(compat, z, out);
}

// Round 8
// 6949.146 us; speedup vs baseline: 1.6999x; 1.6999x over previous
//
#include <hip/hip_runtime.h>

constexpr int kB   = 32;    // batch
constexpr int kNS  = 100;   // n_support
constexpr int kNW  = 10;    // n_way
constexpr int kNZ  = 1000;  // kNS*kNW
constexpr int kD   = 512;   // feature dim
constexpr int kNQ  = 150;   // N*Q query rows
constexpr int kIt  = 15;    // IPM iterations
constexpr int kHalf = 50;
constexpr int kQrt  = 25;   // rows per quarter-strip

// -------------------------------------------------------------------------
// K[b][i][j] = <sup_i, sup_j>  (fp32 accumulate, stored fp64 for the IPM)
__global__ __launch_bounds__(128) void gram_kernel(const float* __restrict__ sup,
                                                   double* __restrict__ K64)
{
    const int i = blockIdx.x;
    const int b = blockIdx.y;
    const int tid = threadIdx.x;
    __shared__ float rowi[kD];
    const float* supb = sup + (size_t)b * kNS * kD;
    reinterpret_cast<float4*>(rowi)[tid] =
        reinterpret_cast<const float4*>(supb + (size_t)i * kD)[tid];
    __syncthreads();
    for (int j = tid; j < kNS; j += 128) {
        const float4* rj = reinterpret_cast<const float4*>(supb + (size_t)j * kD);
        float acc = 0.0f;
        for (int d4 = 0; d4 < kD / 4; ++d4) {
            float4 v = rj[d4];
            acc += rowi[4*d4+0]*v.x + rowi[4*d4+1]*v.y
                 + rowi[4*d4+2]*v.z + rowi[4*d4+3]*v.w;
        }
        K64[((size_t)b * kNS + i) * kNS + j] = (double)acc;
    }
}

// compat[b][i][q] = <sup_i, qry_q>
__global__ __launch_bounds__(256) void compat_kernel(const float* __restrict__ sup,
                                                     const float* __restrict__ qry,
                                                     float* __restrict__ compat)
{
    const int i = blockIdx.x;
    const int b = blockIdx.y;
    const int tid = threadIdx.x;
    __shared__ float rowi[kD];
    const float* supb = sup + (size_t)b * kNS * kD;
    const float* qryb = qry + (size_t)b * kNQ * kD;
    if (tid < 128)
        reinterpret_cast<float4*>(rowi)[tid] =
            reinterpret_cast<const float4*>(supb + (size_t)i * kD)[tid];
    __syncthreads();
    for (int j = tid; j < kNQ; j += 256) {
        const float4* rj = reinterpret_cast<const float4*>(qryb + (size_t)j * kD);
        float acc = 0.0f;
        for (int d4 = 0; d4 < kD / 4; ++d4) {
            float4 v = rj[d4];
            acc += rowi[4*d4+0]*v.x + rowi[4*d4+1]*v.y
                 + rowi[4*d4+2]*v.z + rowi[4*d4+3]*v.w;
        }
        compat[((size_t)b * kNS + i) * kNQ + j] = acc;
    }
}

__global__ __launch_bounds__(256) void init_kernel(double* __restrict__ z,
                                                   double* __restrict__ nu,
                                                   double* __restrict__ s,
                                                   double* __restrict__ lam,
                                                   double* __restrict__ mu_g)
{
    const int b = blockIdx.x;
    const int tid = threadIdx.x;
    for (int m = tid; m < kNZ; m += 256) {
        z[b*kNZ + m]   = 0.0;
        s[b*kNZ + m]   = 1.0;
        lam[b*kNZ + m] = 1.0;
    }
    if (tid < kNS) nu[b*kNS + tid] = 0.0;
    if (tid == 0)  mu_g[b] = 1.0;   // dot(s0,lam0)/kNZ
}

// -------------------------------------------------------------------------
// One block (512 thr = 8 waves) per (b,a): (h=tid>>7 in 0..3, j=tid&127)
// owns rows [h*25, h*25+25) of column j of H_a = K + diag(1 + lam_a/s_a).
// hreg[25] = 50 VGPR -> fits the 512-thread 128-VGPR cap with NO spill.
// Signed pivot-row storage + write-ahead pivot row & pivot reciprocal;
// 1 barrier per pivot; 8 waves/block (+2 blocks/CU) hide the LDS latency.
__global__ __launch_bounds__(512) void ipm_invert_kernel(
    const double* __restrict__ K64, const int* __restrict__ labels,
    const double* __restrict__ z, const double* __restrict__ nu,
    const double* __restrict__ s, const double* __restrict__ lam,
    const double* __restrict__ mu_g,
    double* __restrict__ Hinv, double* __restrict__ tvec)
{
    const int b = blockIdx.x / kNW;
    const int a = blockIdx.x - b * kNW;
    const int tid = threadIdx.x;
    const int h = tid >> 7;
    const int j = tid & 127;
    const bool act = (j < kNS);
    const int base = h * kQrt;

    __shared__ double za[kNS], sa[kNS], la[kNS], da[kNS], nus[kNS], r1s[kNS];
    __shared__ double part4[4][kNS];
    __shared__ double rowk[2][kNS + 8];  // [buf][0..99]=signed row, [100]=pivinv
    __shared__ int    labs[kNS];

    const double* zb = z   + (size_t)b * kNZ;
    const double* sb = s   + (size_t)b * kNZ;
    const double* lb = lam + (size_t)b * kNZ;
    const double* Kb = K64 + (size_t)b * kNS * kNS;

    if (tid < kNS) {
        double zv = zb[tid * kNW + a];
        double sv = sb[tid * kNW + a];
        double lv = lb[tid * kNW + a];
        za[tid] = zv; sa[tid] = sv; la[tid] = lv; da[tid] = lv / sv;
        nus[tid]  = nu[b * kNS + tid];
        labs[tid] = labels[b * kNS + tid];
    }
    __syncthreads();

    // Build H column j (own 25 rows) in registers; fused partial of (K z_a).
    double hreg[kQrt];
    if (act) {
        double kzp = 0.0;
        #pragma unroll
        for (int r = 0; r < kQrt; ++r) {
            const int i = base + r;
            double kv = Kb[(size_t)i * kNS + j];
            kzp += kv * za[i];
            hreg[r] = (i == j) ? (kv + 1.0 + da[j]) : kv;
        }
        part4[h][j] = kzp;
        if (h == 0) {
            rowk[0][j] = hreg[0];                       // seed pivot row 0
            if (j == 0) rowk[0][kNS] = 1.0 / hreg[0];   // seed pivinv
        }
    }
    __syncthreads();
    if (tid < kNS) {
        const double mu = mu_g[b];
        const int i = tid;
        double kz = part4[0][i] + part4[1][i] + part4[2][i] + part4[3][i];
        double yv = (labs[i] == a) ? 1.0 : 0.0;
        double rd = kz + za[i] - yv + la[i] + nus[i];
        double rp = za[i] + sa[i] - 0.1 * yv;      // h = C_REG*y
        double rc = la[i] * sa[i] - 0.1 * mu;      // sigma = 0.1
        r1s[i] = -rd + (rc - la[i] * rp) / sa[i];
    }

    // Gauss-Jordan in-place inverse, 1 barrier per pivot.
    #pragma unroll 1
    for (int k = 0; k < kNS; ++k) {
        const int buf = k & 1, nb2 = 1 - buf;
        __syncthreads();                     // rowk[buf] complete
        if (act) {
            const double P  = rowk[buf][kNS];
            const double Sj = rowk[buf][j];
            const bool jk = (j == k);
            const double sigj  = (j < k) ? -1.0 : 1.0;
            const double nrkj  = jk ? P : sigj * Sj * P;
            const double jkmul = jk ? 0.0 : 1.0;
            #pragma unroll
            for (int c0 = 0; c0 < 2; ++c0) {
                const int off0 = c0 ? 13 : 0;
                const int cnt  = c0 ? 12 : 13;
                double rk[13];
                #pragma unroll
                for (int u = 0; u < 13; ++u)
                    if (u < cnt) rk[u] = rowk[buf][base + off0 + u];
                __builtin_amdgcn_sched_barrier(0);   // keep loads batched
                #pragma unroll
                for (int u = 0; u < 13; ++u) {
                    if (u < cnt) {
                        const int r = off0 + u;
                        const int i = base + r;
                        double he = jkmul * hreg[r];
                        double hn = fma(-rk[u], nrkj, he);
                        hreg[r] = (i == k) ? nrkj : hn;
                        if (i == k + 1) {                        // wave-uniform
                            rowk[nb2][j] = (j <= k) ? -hn : hn;  // signed store
                            if (j == k + 1) rowk[nb2][kNS] = 1.0 / hn;
                        }
                    }
                }
            }
        }
    }

    // Write Hinv (coalesced) + t_a = Hinv * r1 (4-way combine via symmetry)
    double* Hb = Hinv + (size_t)(b * kNW + a) * kNS * kNS;
    if (act) {
        double tp = 0.0;
        #pragma unroll
        for (int r = 0; r < kQrt; ++r) {
            Hb[(size_t)(base + r) * kNS + j] = hreg[r];
            tp += hreg[r] * r1s[base + r];
        }
        part4[h][j] = tp;
    }
    __syncthreads();
    if (tid < kNS)
        tvec[(size_t)(b * kNW + a) * kNS + tid] =
            part4[0][tid] + part4[1][tid] + part4[2][tid] + part4[3][tid];
}

// -------------------------------------------------------------------------
// S[b] = sum_a Hinv_a[b] — full-GPU streaming reduction (320 blocks).
__global__ __launch_bounds__(256) void sbuild_kernel(const double* __restrict__ Hinv,
                                                     double* __restrict__ Sg)
{
    const int b  = blockIdx.x / kNW;
    const int rc = blockIdx.x - b * kNW;
    const int tid = threadIdx.x;
    const double* Hb = Hinv + (size_t)b * kNW * kNS * kNS;
    for (int e = tid; e < kNS * kNS / kNW; e += 256) {
        const int idx = rc * (kNS * kNS / kNW) + e;
        double acc = 0.0;
        #pragma unroll
        for (int a = 0; a < kNW; ++a) acc += Hb[(size_t)a * kNS * kNS + idx];
        Sg[(size_t)b * kNS * kNS + idx] = acc;
    }
}

// -------------------------------------------------------------------------
// One block (512 thr) per b: GJ-solve S dnu = sum_a t_a + rp2. Same strip
// structure as invert; rhs lives in the j==100 threads (never a pivot col).
__global__ __launch_bounds__(512) void schur_solve_kernel(
    const double* __restrict__ Sg, const double* __restrict__ tvec,
    const double* __restrict__ z, double* __restrict__ dnu_g)
{
    const int b = blockIdx.x;
    const int tid = threadIdx.x;
    const int h = tid >> 7;
    const int j = tid & 127;
    const int base = h * kQrt;
    const bool act  = (j < kNS);
    const bool actS = (j <= kNS);

    __shared__ double rhs[kNS];
    __shared__ double rowk[2][kNS + 8]; // [buf][0..99]=row,[100]=rhs,[101]=pivinv

    const double* Sb = Sg   + (size_t)b * kNS * kNS;
    const double* tb = tvec + (size_t)b * kNW * kNS;
    const double* zb = z    + (size_t)b * kNZ;

    if (tid < kNS) {
        double acc = 0.0, rp2 = 0.0;
        #pragma unroll
        for (int a = 0; a < kNW; ++a) {
            acc += tb[a * kNS + tid];
            rp2 += zb[tid * kNW + a];
        }
        rhs[tid] = acc + rp2;
    }
    __syncthreads();

    double sreg[kQrt];
    if (act) {
        #pragma unroll
        for (int r = 0; r < kQrt; ++r)
            sreg[r] = Sb[(size_t)(base + r) * kNS + j];
    } else if (j == kNS) {
        #pragma unroll
        for (int r = 0; r < kQrt; ++r) sreg[r] = rhs[base + r];
    }
    if (actS && h == 0) {
        rowk[0][j] = sreg[0];
        if (j == 0) rowk[0][kNS + 1] = 1.0 / sreg[0];
    }

    #pragma unroll 1
    for (int k = 0; k < kNS; ++k) {
        const int buf = k & 1, nb2 = 1 - buf;
        __syncthreads();
        if (actS) {
            const double P  = rowk[buf][kNS + 1];
            const double Sj = rowk[buf][j];
            const bool jk = (j == k);
            const double sigj  = (j < k) ? -1.0 : 1.0;
            const double nrkj  = jk ? P : sigj * Sj * P;
            const double jkmul = jk ? 0.0 : 1.0;
            #pragma unroll
            for (int c0 = 0; c0 < 2; ++c0) {
                const int off0 = c0 ? 13 : 0;
                const int cnt  = c0 ? 12 : 13;
                double rk[13];
                #pragma unroll
                for (int u = 0; u < 13; ++u)
                    if (u < cnt) rk[u] = rowk[buf][base + off0 + u];
                __builtin_amdgcn_sched_barrier(0);
                #pragma unroll
                for (int u = 0; u < 13; ++u) {
                    if (u < cnt) {
                        const int r = off0 + u;
                        const int i = base + r;
                        double he = jkmul * sreg[r];
                        double hn = fma(-rk[u], nrkj, he);
                        sreg[r] = (i == k) ? nrkj : hn;
                        if (i == k + 1) {
                            rowk[nb2][j] = (j <= k) ? -hn : hn;
                            if (j == k + 1) rowk[nb2][kNS + 1] = 1.0 / hn;
                        }
                    }
                }
            }
        }
    }

    if (j == kNS) {
        #pragma unroll
        for (int r = 0; r < kQrt; ++r)
            dnu_g[(size_t)b * kNS + base + r] = sreg[r];
    }
}

// -------------------------------------------------------------------------
// One block per (b,a): dz_a = t_a - Hinv_a*dnu (full-GPU streaming of Hinv),
// ds/dlam, per-block min step-ratio.
__global__ __launch_bounds__(256) void dz_kernel(
    const int* __restrict__ labels,
    const double* __restrict__ Hinv, const double* __restrict__ tvec,
    const double* __restrict__ dnu_g,
    const double* __restrict__ z, const double* __restrict__ s,
    const double* __restrict__ lam, const double* __restrict__ mu_g,
    double* __restrict__ dz_g, double* __restrict__ ds_g,
    double* __restrict__ dl_g, double* __restrict__ minr_g)
{
    const int b = blockIdx.x / kNW;
    const int a = blockIdx.x - b * kNW;
    const int tid = threadIdx.x;
    const int h = tid >> 7;
    const int j = tid & 127;

    __shared__ double dnus[kNS];
    __shared__ double p2[2][kNS];
    __shared__ double red[256];

    const double* Hb = Hinv + (size_t)(b * kNW + a) * kNS * kNS;

    if (tid < kNS) dnus[tid] = dnu_g[(size_t)b * kNS + tid];
    __syncthreads();

    if (j < kNS) {
        double p = 0.0;
        #pragma unroll
        for (int r = 0; r < kHalf; ++r)
            p += Hb[(size_t)(h * kHalf + r) * kNS + j] * dnus[h * kHalf + r];
        p2[h][j] = p;
    }
    __syncthreads();

    double lmin = 1e300;
    if (tid < kNS) {
        const int i = tid;
        const size_t m = (size_t)b * kNZ + i * kNW + a;
        const double mu = mu_g[b];
        double dz = tvec[(size_t)(b * kNW + a) * kNS + i] - (p2[0][i] + p2[1][i]);
        double yv = (labels[b * kNS + i] == a) ? 1.0 : 0.0;
        double zv = z[m], sv = s[m], lv = lam[m];
        double rp = zv + sv - 0.1 * yv;
        double rc = lv * sv - 0.1 * mu;
        double ds = -rp - dz;
        double dl = (-rc - lv * ds) / sv;
        dz_g[m] = dz; ds_g[m] = ds; dl_g[m] = dl;
        if (ds < 0.0) lmin = fmin(lmin, -sv / ds);
        if (dl < 0.0) lmin = fmin(lmin, -lv / dl);
    }
    red[tid] = lmin; __syncthreads();
    for (int off = 128; off > 0; off >>= 1) {
        if (tid < off) red[tid] = fmin(red[tid], red[tid + off]);
        __syncthreads();
    }
    if (tid == 0) minr_g[b * kNW + a] = red[0];
}

// -------------------------------------------------------------------------
// One block per b: alpha from the 10 per-class mins, state update, next mu.
__global__ __launch_bounds__(256) void update_kernel(
    const double* __restrict__ minr_g, const double* __restrict__ dnu_g,
    const double* __restrict__ dz_g, const double* __restrict__ ds_g,
    const double* __restrict__ dl_g,
    double* __restrict__ z, double* __restrict__ nu,
    double* __restrict__ s, double* __restrict__ lam,
    double* __restrict__ mu_g)
{
    const int b = blockIdx.x;
    const int tid = threadIdx.x;
    __shared__ double red[256];

    double am = 1e300;
    #pragma unroll
    for (int a = 0; a < kNW; ++a) am = fmin(am, minr_g[b * kNW + a]);
    const double alpha = fmin(1.0, 0.99 * am);

    double* zb = z   + (size_t)b * kNZ;
    double* sb = s   + (size_t)b * kNZ;
    double* lb = lam + (size_t)b * kNZ;

    double md = 0.0;
    #pragma unroll
    for (int tcl = 0; tcl < 4; ++tcl) {
        const int  e = tid + tcl * 256;
        const size_t m = (size_t)b * kNZ + e;
        if (e < kNZ) {
            double zn = zb[e] + alpha * dz_g[m];
            double sn = sb[e] + alpha * ds_g[m];
            double ln = lb[e] + alpha * dl_g[m];
            zb[e] = zn; sb[e] = sn; lb[e] = ln;
            md += sn * ln;
        }
    }
    red[tid] = md; __syncthreads();
    for (int off = 128; off > 0; off >>= 1) {
        if (tid < off) red[tid] += red[tid + off];
        __syncthreads();
    }
    if (tid == 0) mu_g[b] = red[0] / kNZ;
    if (tid < kNS) nu[(size_t)b * kNS + tid] += alpha * dnu_g[(size_t)b * kNS + tid];
}

// -------------------------------------------------------------------------
// logits[b][q][n] = sum_s compat[b][s][q] * z[b][s*10+n]
__global__ __launch_bounds__(256) void logits_kernel(const float* __restrict__ compat,
                                                     const double* __restrict__ z,
                                                     float* __restrict__ out)
{
    const int b = blockIdx.x;
    const int tid = threadIdx.x;
    const float* cb = compat + (size_t)b * kNS * kNQ;
    const double* zb = z + (size_t)b * kNZ;
    __shared__ double zs[kNZ];
    for (int m = tid; m < kNZ; m += 256) zs[m] = zb[m];
    __syncthreads();
    for (int idx = tid; idx < kNQ * kNW; idx += 256) {
        int q = idx / kNW, n = idx - q * kNW;
        double acc = 0.0;
        for (int s2 = 0; s2 < kNS; ++s2)
            acc += (double)cb[(size_t)s2 * kNQ + q] * zs[s2 * kNW + n];
        out[(size_t)b * kNQ * kNW + idx] = (float)acc;
    }
}

// -------------------------------------------------------------------------
extern "C" void kernel_launch(void* const* d_in, const int* in_sizes, int n_in,
                              void* d_out, int out_size, void* d_ws, size_t ws_size,
                              hipStream_t stream)
{
    const float* sup    = (const float*)d_in[0];   // (32,10,10,512)
    const int*   labels = (const int*)  d_in[1];   // (32,10,10)
    const float* qry    = (const float*)d_in[2];   // (32,10,15,512)
    float* out = (float*)d_out;                    // (32,150,10) fp32

    char* ws = (char*)d_ws;
    size_t off = 0;
    auto alloc = [&](size_t bytes) -> void* {
        void* p = ws + off;
        off += (bytes + 255) & ~(size_t)255;
        return p;
    };
    double* K64    = (double*)alloc(sizeof(double) * kB * kNS * kNS);        // 2.56 MB
    double* z      = (double*)alloc(sizeof(double) * kB * kNZ);
    double* nu     = (double*)alloc(sizeof(double) * kB * kNS);
    double* s      = (double*)alloc(sizeof(double) * kB * kNZ);
    double* lam    = (double*)alloc(sizeof(double) * kB * kNZ);
    double* mu_g   = (double*)alloc(sizeof(double) * kB);
    double* Hinv   = (double*)alloc(sizeof(double) * kB * kNW * kNS * kNS);  // 25.6 MB
    double* Sg     = (double*)alloc(sizeof(double) * kB * kNS * kNS);        // 2.56 MB
    double* tvec   = (double*)alloc(sizeof(double) * kB * kNW * kNS);
    double* dnu_g  = (double*)alloc(sizeof(double) * kB * kNS);
    double* dz_g   = (double*)alloc(sizeof(double) * kB * kNZ);
    double* ds_g   = (double*)alloc(sizeof(double) * kB * kNZ);
    double* dl_g   = (double*)alloc(sizeof(double) * kB * kNZ);
    double* minr_g = (double*)alloc(sizeof(double) * kB * kNW);
    float*  compat = (float*) alloc(sizeof(float)  * kB * kNS * kNQ);        // 1.92 MB

    gram_kernel  <<<dim3(kNS, kB), 128, 0, stream>>>(sup, K64);
    compat_kernel<<<dim3(kNS, kB), 256, 0, stream>>>(sup, qry, compat);
    init_kernel  <<<kB, 256, 0, stream>>>(z, nu, s, lam, mu_g);

    for (int it = 0; it < kIt; ++it) {
        ipm_invert_kernel<<<kB * kNW, 512, 0, stream>>>(K64, labels, z, nu, s,
                                                        lam, mu_g, Hinv, tvec);
        sbuild_kernel<<<kB * kNW, 256, 0, stream>>>(Hinv, Sg);
        schur_solve_kernel<<<kB, 512, 0, stream>>>(Sg, tvec, z, dnu_g);
        dz_kernel<<<kB * kNW, 256, 0, stream>>>(labels, Hinv, tvec, dnu_g,
                                                z, s, lam, mu_g,
                                                dz_g, ds_g, dl_g, minr_g);
        update_kernel<<<kB, 256, 0, stream>>>(minr_g, dnu_g, dz_g, ds_g, dl_g,
                                              z, nu, s, lam, mu_g);
    }

    logits_kernel<<<kB, 256, 0, stream>>>(compat, z, out);
}

// Round 9
// 4579.098 us; speedup vs baseline: 2.5797x; 1.5176x over previous
//
#include <hip/hip_runtime.h>

constexpr int kB   = 32;    // batch
constexpr int kNS  = 100;   // n_support
constexpr int kNW  = 10;    // n_way
constexpr int kNZ  = 1000;  // kNS*kNW
constexpr int kD   = 512;   // feature dim
constexpr int kNQ  = 150;   // N*Q query rows
constexpr int kIt  = 15;    // IPM iterations
constexpr int kHalf = 50;
constexpr int kQrt  = 25;   // rows per quarter-strip
constexpr int kPan  = 4;    // pivots per panel (barrier amortization)

// -------------------------------------------------------------------------
// K[b][i][j] = <sup_i, sup_j>  (fp32 accumulate, stored fp64 for the IPM)
__global__ __launch_bounds__(128) void gram_kernel(const float* __restrict__ sup,
                                                   double* __restrict__ K64)
{
    const int i = blockIdx.x;
    const int b = blockIdx.y;
    const int tid = threadIdx.x;
    __shared__ float rowi[kD];
    const float* supb = sup + (size_t)b * kNS * kD;
    reinterpret_cast<float4*>(rowi)[tid] =
        reinterpret_cast<const float4*>(supb + (size_t)i * kD)[tid];
    __syncthreads();
    for (int j = tid; j < kNS; j += 128) {
        const float4* rj = reinterpret_cast<const float4*>(supb + (size_t)j * kD);
        float acc = 0.0f;
        for (int d4 = 0; d4 < kD / 4; ++d4) {
            float4 v = rj[d4];
            acc += rowi[4*d4+0]*v.x + rowi[4*d4+1]*v.y
                 + rowi[4*d4+2]*v.z + rowi[4*d4+3]*v.w;
        }
        K64[((size_t)b * kNS + i) * kNS + j] = (double)acc;
    }
}

// compat[b][i][q] = <sup_i, qry_q>
__global__ __launch_bounds__(256) void compat_kernel(const float* __restrict__ sup,
                                                     const float* __restrict__ qry,
                                                     float* __restrict__ compat)
{
    const int i = blockIdx.x;
    const int b = blockIdx.y;
    const int tid = threadIdx.x;
    __shared__ float rowi[kD];
    const float* supb = sup + (size_t)b * kNS * kD;
    const float* qryb = qry + (size_t)b * kNQ * kD;
    if (tid < 128)
        reinterpret_cast<float4*>(rowi)[tid] =
            reinterpret_cast<const float4*>(supb + (size_t)i * kD)[tid];
    __syncthreads();
    for (int j = tid; j < kNQ; j += 256) {
        const float4* rj = reinterpret_cast<const float4*>(qryb + (size_t)j * kD);
        float acc = 0.0f;
        for (int d4 = 0; d4 < kD / 4; ++d4) {
            float4 v = rj[d4];
            acc += rowi[4*d4+0]*v.x + rowi[4*d4+1]*v.y
                 + rowi[4*d4+2]*v.z + rowi[4*d4+3]*v.w;
        }
        compat[((size_t)b * kNS + i) * kNQ + j] = acc;
    }
}

__global__ __launch_bounds__(256) void init_kernel(double* __restrict__ z,
                                                   double* __restrict__ nu,
                                                   double* __restrict__ s,
                                                   double* __restrict__ lam,
                                                   double* __restrict__ mu_g)
{
    const int b = blockIdx.x;
    const int tid = threadIdx.x;
    for (int m = tid; m < kNZ; m += 256) {
        z[b*kNZ + m]   = 0.0;
        s[b*kNZ + m]   = 1.0;
        lam[b*kNZ + m] = 1.0;
    }
    if (tid < kNS) nu[b*kNS + tid] = 0.0;
    if (tid == 0)  mu_g[b] = 1.0;   // dot(s0,lam0)/kNZ
}

// -------------------------------------------------------------------------
// Panel solve helper: LU of 4x4 SPD block B (no pivoting) + solve B m = rhs.
// All in registers, fully unrolled.
__device__ __forceinline__ void lu4_solve(double B[4][4],
                                          double b0, double b1, double b2, double b3,
                                          double& m0, double& m1, double& m2, double& m3)
{
    const double d0 = 1.0 / B[0][0];
    const double l10 = B[1][0]*d0, l20 = B[2][0]*d0, l30 = B[3][0]*d0;
    B[1][1] -= l10*B[0][1]; B[1][2] -= l10*B[0][2]; B[1][3] -= l10*B[0][3];
    B[2][1] -= l20*B[0][1]; B[2][2] -= l20*B[0][2]; B[2][3] -= l20*B[0][3];
    B[3][1] -= l30*B[0][1]; B[3][2] -= l30*B[0][2]; B[3][3] -= l30*B[0][3];
    const double d1 = 1.0 / B[1][1];
    const double l21 = B[2][1]*d1, l31 = B[3][1]*d1;
    B[2][2] -= l21*B[1][2]; B[2][3] -= l21*B[1][3];
    B[3][2] -= l31*B[1][2]; B[3][3] -= l31*B[1][3];
    const double d2 = 1.0 / B[2][2];
    const double l32 = B[3][2]*d2;
    B[3][3] -= l32*B[2][3];
    const double d3 = 1.0 / B[3][3];
    const double y0 = b0;
    const double y1 = b1 - l10*y0;
    const double y2 = b2 - l20*y0 - l21*y1;
    const double y3 = b3 - l30*y0 - l31*y1 - l32*y2;
    m3 = y3 * d3;
    m2 = (y2 - B[2][3]*m3) * d2;
    m1 = (y1 - B[1][2]*m2 - B[1][3]*m3) * d1;
    m0 = (y0 - B[0][1]*m1 - B[0][2]*m2 - B[0][3]*m3) * d0;
}

// Rank-4 update of the 25 owned rows from signed panel rows in LDS.
// hreg[r] = s*hreg[r] - sum_p sig_i*W[p][i]*m[p]  (sig pre-applied in Wsg)
#define PANEL_UPDATE(SREGARR, WSG, BUF, BASE, SCL, M0, M1, M2, M3)            \
    {                                                                          \
        _Pragma("unroll")                                                      \
        for (int r = 0; r < kQrt; ++r) SREGARR[r] *= SCL;                      \
        _Pragma("unroll")                                                      \
        for (int p = 0; p < kPan; ++p) {                                       \
            const double mp = (p==0) ? M0 : (p==1) ? M1 : (p==2) ? M2 : M3;    \
            _Pragma("unroll")                                                  \
            for (int c0 = 0; c0 < 2; ++c0) {                                   \
                const int off0 = c0 ? 13 : 0;                                  \
                const int cnt  = c0 ? 12 : 13;                                 \
                double w[13];                                                  \
                _Pragma("unroll")                                              \
                for (int u = 0; u < 13; ++u)                                   \
                    if (u < cnt) w[u] = WSG[BUF][p][BASE + off0 + u];          \
                __builtin_amdgcn_sched_barrier(0);                             \
                _Pragma("unroll")                                              \
                for (int u = 0; u < 13; ++u)                                   \
                    if (u < cnt)                                               \
                        SREGARR[off0+u] = fma(-mp, w[u], SREGARR[off0+u]);     \
            }                                                                  \
        }                                                                      \
    }

// -------------------------------------------------------------------------
// One block (512 thr = 8 waves) per (b,a): (h=tid>>7, j=tid&127) owns rows
// [h*25, h*25+25) of column j of H_a = K + diag(1 + lam_a/s_a).
// Panel-blocked GJ: 4 pivots per barrier (25 barriers), block formulas
// B->B^-1, R->B^-1 R, C->-CB^-1, D->D-CB^-1R; C recovered from panel ROWS
// via the symmetric-GJ sign invariant, pre-applied in a signed LDS copy.
__global__ __launch_bounds__(512) void ipm_invert_kernel(
    const double* __restrict__ K64, const int* __restrict__ labels,
    const double* __restrict__ z, const double* __restrict__ nu,
    const double* __restrict__ s, const double* __restrict__ lam,
    const double* __restrict__ mu_g,
    double* __restrict__ Hinv, double* __restrict__ tvec)
{
    const int b = blockIdx.x / kNW;
    const int a = blockIdx.x - b * kNW;
    const int tid = threadIdx.x;
    const int h = tid >> 7;
    const int j = tid & 127;
    const bool act = (j < kNS);
    const int base = h * kQrt;

    __shared__ double za[kNS], sa[kNS], la[kNS], da[kNS], nus[kNS], r1s[kNS];
    __shared__ double part4[4][kNS];
    __shared__ alignas(16) double Wr [2][kPan][kNS + 8];  // raw panel rows
    __shared__ alignas(16) double Wsg[2][kPan][kNS + 8];  // signed panel rows
    __shared__ int labs[kNS];

    const double* zb = z   + (size_t)b * kNZ;
    const double* sb = s   + (size_t)b * kNZ;
    const double* lb = lam + (size_t)b * kNZ;
    const double* Kb = K64 + (size_t)b * kNS * kNS;

    if (tid < kNS) {
        double zv = zb[tid * kNW + a];
        double sv = sb[tid * kNW + a];
        double lv = lb[tid * kNW + a];
        za[tid] = zv; sa[tid] = sv; la[tid] = lv; da[tid] = lv / sv;
        nus[tid]  = nu[b * kNS + tid];
        labs[tid] = labels[b * kNS + tid];
    }
    __syncthreads();

    // Build H column j (own 25 rows) in registers; fused partial of (K z_a).
    double hreg[kQrt];
    if (act) {
        double kzp = 0.0;
        #pragma unroll
        for (int r = 0; r < kQrt; ++r) {
            const int i = base + r;
            double kv = Kb[(size_t)i * kNS + j];
            kzp += kv * za[i];
            hreg[r] = (i == j) ? (kv + 1.0 + da[j]) : kv;
        }
        part4[h][j] = kzp;
        if (h == 0) {   // seed panel 0 rows (0..3); sign vs k0=0 -> all +
            #pragma unroll
            for (int p = 0; p < kPan; ++p) {
                Wr [0][p][j] = hreg[p];
                Wsg[0][p][j] = hreg[p];
            }
        }
    }
    __syncthreads();
    if (tid < kNS) {
        const double mu = mu_g[b];
        const int i = tid;
        double kz = part4[0][i] + part4[1][i] + part4[2][i] + part4[3][i];
        double yv = (labs[i] == a) ? 1.0 : 0.0;
        double rd = kz + za[i] - yv + la[i] + nus[i];
        double rp = za[i] + sa[i] - 0.1 * yv;      // h = C_REG*y
        double rc = la[i] * sa[i] - 0.1 * mu;      // sigma = 0.1
        r1s[i] = -rd + (rc - la[i] * rp) / sa[i];
    }

    // Panel-blocked Gauss-Jordan inverse: 25 panels, 1 barrier each.
    #pragma unroll 1
    for (int k0 = 0; k0 < kNS; k0 += kPan) {
        const int buf = (k0 >> 2) & 1, nbuf = 1 - buf;
        __syncthreads();                     // Wr/Wsg[buf] complete
        if (act) {
            // B = panel rows x panel cols (raw, broadcast reads)
            double B[4][4];
            #pragma unroll
            for (int p = 0; p < 4; ++p)
                #pragma unroll
                for (int q = 0; q < 4; ++q)
                    B[p][q] = Wr[buf][p][k0 + q];
            // rhs: e_q for panel columns, else panel-row entries of col j
            const bool inpan = (j >= k0) && (j < k0 + kPan);
            const int  q     = j - k0;
            double b0 = inpan ? (q == 0 ? 1.0 : 0.0) : Wr[buf][0][j];
            double b1 = inpan ? (q == 1 ? 1.0 : 0.0) : Wr[buf][1][j];
            double b2 = inpan ? (q == 2 ? 1.0 : 0.0) : Wr[buf][2][j];
            double b3 = inpan ? (q == 3 ? 1.0 : 0.0) : Wr[buf][3][j];
            double m0, m1, m2, m3;
            lu4_solve(B, b0, b1, b2, b3, m0, m1, m2, m3);

            const double scl = inpan ? 0.0 : 1.0;
            PANEL_UPDATE(hreg, Wsg, buf, base, scl, m0, m1, m2, m3);

            // panel rows get m directly (overwrite generic update)
            if (k0 < base + kQrt && k0 + kPan - 1 >= base) {
                #pragma unroll
                for (int r = 0; r < kQrt; ++r) {
                    const int i = base + r;
                    if (i >= k0 && i < k0 + kPan) {
                        const int p = i - k0;
                        hreg[r] = (p==0) ? m0 : (p==1) ? m1 : (p==2) ? m2 : m3;
                    }
                }
            }
            // write-ahead next panel rows (raw + signed vs kn0)
            const int kn0 = k0 + kPan;
            if (kn0 < kNS && kn0 < base + kQrt && kn0 + kPan - 1 >= base) {
                #pragma unroll
                for (int r = 0; r < kQrt; ++r) {
                    const int i = base + r;
                    if (i >= kn0 && i < kn0 + kPan) {
                        const int p = i - kn0;
                        Wr [nbuf][p][j] = hreg[r];
                        Wsg[nbuf][p][j] = (j < kn0) ? -hreg[r] : hreg[r];
                    }
                }
            }
        }
    }

    // Write Hinv (coalesced) + t_a = Hinv * r1 (4-way combine via symmetry)
    double* Hb = Hinv + (size_t)(b * kNW + a) * kNS * kNS;
    if (act) {
        double tp = 0.0;
        #pragma unroll
        for (int r = 0; r < kQrt; ++r) {
            Hb[(size_t)(base + r) * kNS + j] = hreg[r];
            tp += hreg[r] * r1s[base + r];
        }
        part4[h][j] = tp;
    }
    __syncthreads();
    if (tid < kNS)
        tvec[(size_t)(b * kNW + a) * kNS + tid] =
            part4[0][tid] + part4[1][tid] + part4[2][tid] + part4[3][tid];
}

// -------------------------------------------------------------------------
// S[b] = sum_a Hinv_a[b] — full-GPU streaming reduction (320 blocks).
__global__ __launch_bounds__(256) void sbuild_kernel(const double* __restrict__ Hinv,
                                                     double* __restrict__ Sg)
{
    const int b  = blockIdx.x / kNW;
    const int rc = blockIdx.x - b * kNW;
    const int tid = threadIdx.x;
    const double* Hb = Hinv + (size_t)b * kNW * kNS * kNS;
    for (int e = tid; e < kNS * kNS / kNW; e += 256) {
        const int idx = rc * (kNS * kNS / kNW) + e;
        double acc = 0.0;
        #pragma unroll
        for (int a = 0; a < kNW; ++a) acc += Hb[(size_t)a * kNS * kNS + idx];
        Sg[(size_t)b * kNS * kNS + idx] = acc;
    }
}

// -------------------------------------------------------------------------
// One block (512 thr) per b: panel-blocked GJ solve S dnu = sum_a t_a + rp2.
// rhs is column 100 (j==100 threads; never a pivot column).
__global__ __launch_bounds__(512) void schur_solve_kernel(
    const double* __restrict__ Sg, const double* __restrict__ tvec,
    const double* __restrict__ z, double* __restrict__ dnu_g)
{
    const int b = blockIdx.x;
    const int tid = threadIdx.x;
    const int h = tid >> 7;
    const int j = tid & 127;
    const int base = h * kQrt;
    const bool act  = (j < kNS);
    const bool actS = (j <= kNS);

    __shared__ double rhs[kNS];
    __shared__ alignas(16) double Wr [2][kPan][kNS + 8];
    __shared__ alignas(16) double Wsg[2][kPan][kNS + 8];

    const double* Sb = Sg   + (size_t)b * kNS * kNS;
    const double* tb = tvec + (size_t)b * kNW * kNS;
    const double* zb = z    + (size_t)b * kNZ;

    if (tid < kNS) {
        double acc = 0.0, rp2 = 0.0;
        #pragma unroll
        for (int a = 0; a < kNW; ++a) {
            acc += tb[a * kNS + tid];
            rp2 += zb[tid * kNW + a];
        }
        rhs[tid] = acc + rp2;
    }
    __syncthreads();

    double sreg[kQrt];
    if (act) {
        #pragma unroll
        for (int r = 0; r < kQrt; ++r)
            sreg[r] = Sb[(size_t)(base + r) * kNS + j];
    } else if (j == kNS) {
        #pragma unroll
        for (int r = 0; r < kQrt; ++r) sreg[r] = rhs[base + r];
    }
    if (actS && h == 0) {
        #pragma unroll
        for (int p = 0; p < kPan; ++p) {
            Wr [0][p][j] = sreg[p];
            Wsg[0][p][j] = sreg[p];
        }
    }

    #pragma unroll 1
    for (int k0 = 0; k0 < kNS; k0 += kPan) {
        const int buf = (k0 >> 2) & 1, nbuf = 1 - buf;
        __syncthreads();
        if (actS) {
            double B[4][4];
            #pragma unroll
            for (int p = 0; p < 4; ++p)
                #pragma unroll
                for (int q = 0; q < 4; ++q)
                    B[p][q] = Wr[buf][p][k0 + q];
            const bool inpan = (j >= k0) && (j < k0 + kPan);  // j==100 never
            const int  q     = j - k0;
            double b0 = inpan ? (q == 0 ? 1.0 : 0.0) : Wr[buf][0][j];
            double b1 = inpan ? (q == 1 ? 1.0 : 0.0) : Wr[buf][1][j];
            double b2 = inpan ? (q == 2 ? 1.0 : 0.0) : Wr[buf][2][j];
            double b3 = inpan ? (q == 3 ? 1.0 : 0.0) : Wr[buf][3][j];
            double m0, m1, m2, m3;
            lu4_solve(B, b0, b1, b2, b3, m0, m1, m2, m3);

            const double scl = inpan ? 0.0 : 1.0;
            PANEL_UPDATE(sreg, Wsg, buf, base, scl, m0, m1, m2, m3);

            if (k0 < base + kQrt && k0 + kPan - 1 >= base) {
                #pragma unroll
                for (int r = 0; r < kQrt; ++r) {
                    const int i = base + r;
                    if (i >= k0 && i < k0 + kPan) {
                        const int p = i - k0;
                        sreg[r] = (p==0) ? m0 : (p==1) ? m1 : (p==2) ? m2 : m3;
                    }
                }
            }
            const int kn0 = k0 + kPan;
            if (kn0 < kNS && kn0 < base + kQrt && kn0 + kPan - 1 >= base) {
                #pragma unroll
                for (int r = 0; r < kQrt; ++r) {
                    const int i = base + r;
                    if (i >= kn0 && i < kn0 + kPan) {
                        const int p = i - kn0;
                        Wr [nbuf][p][j] = sreg[r];
                        Wsg[nbuf][p][j] = (j < kn0) ? -sreg[r] : sreg[r];
                    }
                }
            }
        }
    }

    if (j == kNS) {
        #pragma unroll
        for (int r = 0; r < kQrt; ++r)
            dnu_g[(size_t)b * kNS + base + r] = sreg[r];
    }
}

// -------------------------------------------------------------------------
// One block per (b,a): dz_a = t_a - Hinv_a*dnu (full-GPU streaming of Hinv),
// ds/dlam, per-block min step-ratio.
__global__ __launch_bounds__(256) void dz_kernel(
    const int* __restrict__ labels,
    const double* __restrict__ Hinv, const double* __restrict__ tvec,
    const double* __restrict__ dnu_g,
    const double* __restrict__ z, const double* __restrict__ s,
    const double* __restrict__ lam, const double* __restrict__ mu_g,
    double* __restrict__ dz_g, double* __restrict__ ds_g,
    double* __restrict__ dl_g, double* __restrict__ minr_g)
{
    const int b = blockIdx.x / kNW;
    const int a = blockIdx.x - b * kNW;
    const int tid = threadIdx.x;
    const int h = tid >> 7;
    const int j = tid & 127;

    __shared__ double dnus[kNS];
    __shared__ double p2[2][kNS];
    __shared__ double red[256];

    const double* Hb = Hinv + (size_t)(b * kNW + a) * kNS * kNS;

    if (tid < kNS) dnus[tid] = dnu_g[(size_t)b * kNS + tid];
    __syncthreads();

    if (j < kNS) {
        double p = 0.0;
        #pragma unroll
        for (int r = 0; r < kHalf; ++r)
            p += Hb[(size_t)(h * kHalf + r) * kNS + j] * dnus[h * kHalf + r];
        p2[h][j] = p;
    }
    __syncthreads();

    double lmin = 1e300;
    if (tid < kNS) {
        const int i = tid;
        const size_t m = (size_t)b * kNZ + i * kNW + a;
        const double mu = mu_g[b];
        double dz = tvec[(size_t)(b * kNW + a) * kNS + i] - (p2[0][i] + p2[1][i]);
        double yv = (labels[b * kNS + i] == a) ? 1.0 : 0.0;
        double zv = z[m], sv = s[m], lv = lam[m];
        double rp = zv + sv - 0.1 * yv;
        double rc = lv * sv - 0.1 * mu;
        double ds = -rp - dz;
        double dl = (-rc - lv * ds) / sv;
        dz_g[m] = dz; ds_g[m] = ds; dl_g[m] = dl;
        if (ds < 0.0) lmin = fmin(lmin, -sv / ds);
        if (dl < 0.0) lmin = fmin(lmin, -lv / dl);
    }
    red[tid] = lmin; __syncthreads();
    for (int off = 128; off > 0; off >>= 1) {
        if (tid < off) red[tid] = fmin(red[tid], red[tid + off]);
        __syncthreads();
    }
    if (tid == 0) minr_g[b * kNW + a] = red[0];
}

// -------------------------------------------------------------------------
// One block per b: alpha from the 10 per-class mins, state update, next mu.
__global__ __launch_bounds__(256) void update_kernel(
    const double* __restrict__ minr_g, const double* __restrict__ dnu_g,
    const double* __restrict__ dz_g, const double* __restrict__ ds_g,
    const double* __restrict__ dl_g,
    double* __restrict__ z, double* __restrict__ nu,
    double* __restrict__ s, double* __restrict__ lam,
    double* __restrict__ mu_g)
{
    const int b = blockIdx.x;
    const int tid = threadIdx.x;
    __shared__ double red[256];

    double am = 1e300;
    #pragma unroll
    for (int a = 0; a < kNW; ++a) am = fmin(am, minr_g[b * kNW + a]);
    const double alpha = fmin(1.0, 0.99 * am);

    double* zb = z   + (size_t)b * kNZ;
    double* sb = s   + (size_t)b * kNZ;
    double* lb = lam + (size_t)b * kNZ;

    double md = 0.0;
    #pragma unroll
    for (int tcl = 0; tcl < 4; ++tcl) {
        const int  e = tid + tcl * 256;
        const size_t m = (size_t)b * kNZ + e;
        if (e < kNZ) {
            double zn = zb[e] + alpha * dz_g[m];
            double sn = sb[e] + alpha * ds_g[m];
            double ln = lb[e] + alpha * dl_g[m];
            zb[e] = zn; sb[e] = sn; lb[e] = ln;
            md += sn * ln;
        }
    }
    red[tid] = md; __syncthreads();
    for (int off = 128; off > 0; off >>= 1) {
        if (tid < off) red[tid] += red[tid + off];
        __syncthreads();
    }
    if (tid == 0) mu_g[b] = red[0] / kNZ;
    if (tid < kNS) nu[(size_t)b * kNS + tid] += alpha * dnu_g[(size_t)b * kNS + tid];
}

// -------------------------------------------------------------------------
// logits[b][q][n] = sum_s compat[b][s][q] * z[b][s*10+n]
__global__ __launch_bounds__(256) void logits_kernel(const float* __restrict__ compat,
                                                     const double* __restrict__ z,
                                                     float* __restrict__ out)
{
    const int b = blockIdx.x;
    const int tid = threadIdx.x;
    const float* cb = compat + (size_t)b * kNS * kNQ;
    const double* zb = z + (size_t)b * kNZ;
    __shared__ double zs[kNZ];
    for (int m = tid; m < kNZ; m += 256) zs[m] = zb[m];
    __syncthreads();
    for (int idx = tid; idx < kNQ * kNW; idx += 256) {
        int q = idx / kNW, n = idx - q * kNW;
        double acc = 0.0;
        for (int s2 = 0; s2 < kNS; ++s2)
            acc += (double)cb[(size_t)s2 * kNQ + q] * zs[s2 * kNW + n];
        out[(size_t)b * kNQ * kNW + idx] = (float)acc;
    }
}

// -------------------------------------------------------------------------
extern "C" void kernel_launch(void* const* d_in, const int* in_sizes, int n_in,
                              void* d_out, int out_size, void* d_ws, size_t ws_size,
                              hipStream_t stream)
{
    const float* sup    = (const float*)d_in[0];   // (32,10,10,512)
    const int*   labels = (const int*)  d_in[1];   // (32,10,10)
    const float* qry    = (const float*)d_in[2];   // (32,10,15,512)
    float* out = (float*)d_out;                    // (32,150,10) fp32

    char* ws = (char*)d_ws;
    size_t off = 0;
    auto alloc = [&](size_t bytes) -> void* {
        void* p = ws + off;
        off += (bytes + 255) & ~(size_t)255;
        return p;
    };
    double* K64    = (double*)alloc(sizeof(double) * kB * kNS * kNS);        // 2.56 MB
    double* z      = (double*)alloc(sizeof(double) * kB * kNZ);
    double* nu     = (double*)alloc(sizeof(double) * kB * kNS);
    double* s      = (double*)alloc(sizeof(double) * kB * kNZ);
    double* lam    = (double*)alloc(sizeof(double) * kB * kNZ);
    double* mu_g   = (double*)alloc(sizeof(double) * kB);
    double* Hinv   = (double*)alloc(sizeof(double) * kB * kNW * kNS * kNS);  // 25.6 MB
    double* Sg     = (double*)alloc(sizeof(double) * kB * kNS * kNS);        // 2.56 MB
    double* tvec   = (double*)alloc(sizeof(double) * kB * kNW * kNS);
    double* dnu_g  = (double*)alloc(sizeof(double) * kB * kNS);
    double* dz_g   = (double*)alloc(sizeof(double) * kB * kNZ);
    double* ds_g   = (double*)alloc(sizeof(double) * kB * kNZ);
    double* dl_g   = (double*)alloc(sizeof(double) * kB * kNZ);
    double* minr_g = (double*)alloc(sizeof(double) * kB * kNW);
    float*  compat = (float*) alloc(sizeof(float)  * kB * kNS * kNQ);        // 1.92 MB

    gram_kernel  <<<dim3(kNS, kB), 128, 0, stream>>>(sup, K64);
    compat_kernel<<<dim3(kNS, kB), 256, 0, stream>>>(sup, qry, compat);
    init_kernel  <<<kB, 256, 0, stream>>>(z, nu, s, lam, mu_g);

    for (int it = 0; it < kIt; ++it) {
        ipm_invert_kernel<<<kB * kNW, 512, 0, stream>>>(K64, labels, z, nu, s,
                                                        lam, mu_g, Hinv, tvec);
        sbuild_kernel<<<kB * kNW, 256, 0, stream>>>(Hinv, Sg);
        schur_solve_kernel<<<kB, 512, 0, stream>>>(Sg, tvec, z, dnu_g);
        dz_kernel<<<kB * kNW, 256, 0, stream>>>(labels, Hinv, tvec, dnu_g,
                                                z, s, lam, mu_g,
                                                dz_g, ds_g, dl_g, minr_g);
        update_kernel<<<kB, 256, 0, stream>>>(minr_g, dnu_g, dz_g, ds_g, dl_g,
                                              z, nu, s, lam, mu_g);
    }

    logits_kernel<<<kB, 256, 0, stream>>>(compat, z, out);
}